// Round 5
// baseline (348.754 us; speedup 1.0000x reference)
//
#include <hip/hip_runtime.h>
#include <stdint.h>

// Algebra (validated R3/R4): only the cls token queries.
//   q = x0 @ Wq + bq                         (256 x 512)
//   r[s][h*512+j] = sum_c q[s][h*64+c] * Wk[j][h*64+c]   (q.k logits vector)
//   logits = (r . x_n)/8  (+ q.bk const dropped: softmax-invariant)
//   p = softmax ; y_h = sum_n p_h[n] x[n]
//   ctx = y @ Wv + bv (per-head k-slice) ; out = ctx @ Wo + bo
// R5: direct factor form — no A/G precompute, no part-reduce. All fp32.

// ---------------- K1: fused q + r. grid (16 it, 8 h) ----------------
__global__ __launch_bounds__(256) void qr_kernel(
    const float* __restrict__ x, const float* __restrict__ Wq,
    const float* __restrict__ bq, const float* __restrict__ Wk,
    float* __restrict__ r_all) {
  const int it = blockIdx.x;
  const int h  = blockIdx.y;
  const int t  = threadIdx.x;

  __shared__ float x0_s[16][520];
  __shared__ float q_s[16][68];
  __shared__ float wk_ts[64][68];   // [c][j_local]

  // stage x0 rows (cls tokens) it*16 .. it*16+15
#pragma unroll
  for (int l = 0; l < 8; ++l) {
    int flat4 = t + l * 256;
    int row = flat4 >> 7;
    int c4 = (flat4 & 127) * 4;
    float4 v = *(const float4*)&x[((long)(it * 16 + row) * 256) * 512 + c4];
    x0_s[row][c4] = v.x; x0_s[row][c4 + 1] = v.y;
    x0_s[row][c4 + 2] = v.z; x0_s[row][c4 + 3] = v.w;
  }
  __syncthreads();

  // q[row][c0..c0+3] = bq + x0 @ Wq_h
  {
    const int c0 = (t & 15) * 4;
    const int row = t >> 4;
    float4 acc = *(const float4*)&bq[h * 64 + c0];
    for (int k = 0; k < 512; ++k) {
      float xv = x0_s[row][k];
      float4 w4 = *(const float4*)&Wq[(long)k * 512 + h * 64 + c0];
      acc.x += xv * w4.x; acc.y += xv * w4.y;
      acc.z += xv * w4.z; acc.w += xv * w4.w;
    }
    q_s[row][c0] = acc.x; q_s[row][c0 + 1] = acc.y;
    q_s[row][c0 + 2] = acc.z; q_s[row][c0 + 3] = acc.w;
  }

  // r[row][h*512 + j] = sum_c q[row][c] * Wk[j][h*64+c], j in 8 chunks of 64
  for (int jc = 0; jc < 8; ++jc) {
    __syncthreads();
#pragma unroll
    for (int l = 0; l < 4; ++l) {
      int flat4 = t + l * 256;
      int jrow = flat4 >> 4;
      int c4 = (flat4 & 15) * 4;
      float4 v = *(const float4*)&Wk[(long)(jc * 64 + jrow) * 512 + h * 64 + c4];
      wk_ts[c4][jrow] = v.x; wk_ts[c4 + 1][jrow] = v.y;
      wk_ts[c4 + 2][jrow] = v.z; wk_ts[c4 + 3][jrow] = v.w;
    }
    __syncthreads();

    const int jl0 = (t & 15) * 4;
    const int row = t >> 4;
    float4 acc = make_float4(0.f, 0.f, 0.f, 0.f);
    for (int c = 0; c < 64; ++c) {
      float qv = q_s[row][c];
      float4 w4 = *(const float4*)&wk_ts[c][jl0];
      acc.x += qv * w4.x; acc.y += qv * w4.y;
      acc.z += qv * w4.z; acc.w += qv * w4.w;
    }
    *(float4*)&r_all[(long)(it * 16 + row) * 4096 + h * 512 + jc * 64 + jl0] = acc;
  }
}

// ---------------- K2: logits. grid (256 bs, 4 nt), wave-per-token --------------
__global__ __launch_bounds__(256) void logits_kernel(
    const float* __restrict__ x, const float* __restrict__ r_all,
    float* __restrict__ L) {
  const int bs = blockIdx.x;
  const int nt = blockIdx.y;
  const int t = threadIdx.x;
  const int w = t >> 6, lane = t & 63;

  float rv[8][8];
  const float* rb = r_all + (long)bs * 4096 + lane * 8;
#pragma unroll
  for (int h = 0; h < 8; ++h) {
    float4 a = *(const float4*)&rb[h * 512];
    float4 b = *(const float4*)&rb[h * 512 + 4];
    rv[h][0] = a.x; rv[h][1] = a.y; rv[h][2] = a.z; rv[h][3] = a.w;
    rv[h][4] = b.x; rv[h][5] = b.y; rv[h][6] = b.z; rv[h][7] = b.w;
  }

  for (int i = 0; i < 16; ++i) {
    const int n = nt * 64 + w * 16 + i;
    const float* xr = x + ((long)bs * 256 + n) * 512 + lane * 8;
    float4 xa = *(const float4*)xr;
    float4 xb = *(const float4*)(xr + 4);
    float acc[8];
#pragma unroll
    for (int h = 0; h < 8; ++h)
      acc[h] = xa.x * rv[h][0] + xa.y * rv[h][1] + xa.z * rv[h][2] + xa.w * rv[h][3]
             + xb.x * rv[h][4] + xb.y * rv[h][5] + xb.z * rv[h][6] + xb.w * rv[h][7];
#pragma unroll
    for (int h = 0; h < 8; ++h)
      for (int off = 32; off; off >>= 1)
        acc[h] += __shfl_xor(acc[h], off);
    if (lane < 8) {
      float v = acc[0];
#pragma unroll
      for (int h = 1; h < 8; ++h) v = (lane == h) ? acc[h] : v;
      L[((long)bs * 8 + lane) * 256 + n] = v * 0.125f;
    }
  }
}

// ---------------- K3: softmax + Y. grid (256 bs, 4 dt), 128 thr ----------------
__global__ __launch_bounds__(128) void y_kernel(
    const float* __restrict__ x, const float* __restrict__ L,
    float* __restrict__ Y) {
  const int bs = blockIdx.x;
  const int dt = blockIdx.y;
  const int t = threadIdx.x;
  const int w = t >> 6, lane = t & 63;
  __shared__ float p_s[8][256];

#pragma unroll
  for (int hh = 0; hh < 4; ++hh) {
    const int h = w * 4 + hh;
    float4 l4 = *(const float4*)&L[((long)bs * 8 + h) * 256 + lane * 4];
    float m = fmaxf(fmaxf(l4.x, l4.y), fmaxf(l4.z, l4.w));
    for (int o = 32; o; o >>= 1) m = fmaxf(m, __shfl_xor(m, o));
    float e0 = __expf(l4.x - m), e1 = __expf(l4.y - m);
    float e2 = __expf(l4.z - m), e3 = __expf(l4.w - m);
    float s = e0 + e1 + e2 + e3;
    for (int o = 32; o; o >>= 1) s += __shfl_xor(s, o);
    const float inv = 1.f / s;
    float4 p4 = make_float4(e0 * inv, e1 * inv, e2 * inv, e3 * inv);
    *(float4*)&p_s[h][lane * 4] = p4;
  }
  __syncthreads();

  const int d = dt * 128 + t;
  float acc[8] = {};
  const float* xb = x + (long)bs * 256 * 512 + d;
  for (int n0 = 0; n0 < 256; n0 += 4) {
    float xv0 = xb[(long)(n0 + 0) * 512];
    float xv1 = xb[(long)(n0 + 1) * 512];
    float xv2 = xb[(long)(n0 + 2) * 512];
    float xv3 = xb[(long)(n0 + 3) * 512];
#pragma unroll
    for (int h = 0; h < 8; ++h) {
      float4 p4 = *(const float4*)&p_s[h][n0];
      acc[h] += p4.x * xv0 + p4.y * xv1 + p4.z * xv2 + p4.w * xv3;
    }
  }
#pragma unroll
  for (int h = 0; h < 8; ++h)
    Y[(long)bs * 4096 + h * 512 + d] = acc[h];
}

// ---------------- K4: ctx = y @ Wv + bv. grid (16 it, 8 jt=h) ------------------
__global__ __launch_bounds__(256) void ctx_kernel(
    const float* __restrict__ Y, const float* __restrict__ Wv,
    const float* __restrict__ bv, float* __restrict__ ctx) {
  const int it = blockIdx.x;
  const int jt = blockIdx.y;   // = head h, owns cols [jt*64, jt*64+64)
  const int t = threadIdx.x;
  __shared__ float y_s[16][520];

#pragma unroll
  for (int l = 0; l < 8; ++l) {
    int flat4 = t + l * 256;
    int row = flat4 >> 7;
    int c4 = (flat4 & 127) * 4;
    float4 v = *(const float4*)&Y[(long)(it * 16 + row) * 4096 + jt * 512 + c4];
    y_s[row][c4] = v.x; y_s[row][c4 + 1] = v.y;
    y_s[row][c4 + 2] = v.z; y_s[row][c4 + 3] = v.w;
  }
  __syncthreads();

  const int c0 = jt * 64 + (t & 15) * 4;
  const int row = t >> 4;
  float4 acc = *(const float4*)&bv[c0];
  for (int k = 0; k < 512; ++k) {
    float yv = y_s[row][k];
    float4 w4 = *(const float4*)&Wv[(long)k * 512 + c0];
    acc.x += yv * w4.x; acc.y += yv * w4.y;
    acc.z += yv * w4.z; acc.w += yv * w4.w;
  }
  *(float4*)&ctx[(long)(it * 16 + row) * 512 + c0] = acc;
}

// ---------------- K5: out = ctx @ Wo + bo. grid (16 it, 8 jt) ------------------
__global__ __launch_bounds__(256) void out_kernel(
    const float* __restrict__ ctx, const float* __restrict__ Wo,
    const float* __restrict__ bo, float* __restrict__ out) {
  const int it = blockIdx.x;
  const int jt = blockIdx.y;
  const int t = threadIdx.x;
  __shared__ float c_s[16][520];

#pragma unroll
  for (int l = 0; l < 8; ++l) {
    int flat4 = t + l * 256;
    int row = flat4 >> 7;
    int c4 = (flat4 & 127) * 4;
    float4 v = *(const float4*)&ctx[(long)(it * 16 + row) * 512 + c4];
    c_s[row][c4] = v.x; c_s[row][c4 + 1] = v.y;
    c_s[row][c4 + 2] = v.z; c_s[row][c4 + 3] = v.w;
  }
  __syncthreads();

  const int j0 = jt * 64 + (t & 15) * 4;
  const int row = t >> 4;
  float4 acc = *(const float4*)&bo[j0];
  for (int k = 0; k < 512; ++k) {
    float cv = c_s[row][k];
    float4 w4 = *(const float4*)&Wo[(long)k * 512 + j0];
    acc.x += cv * w4.x; acc.y += cv * w4.y;
    acc.z += cv * w4.z; acc.w += cv * w4.w;
  }
  *(float4*)&out[(long)(it * 16 + row) * 512 + j0] = acc;
}

extern "C" void kernel_launch(void* const* d_in, const int* in_sizes, int n_in,
                              void* d_out, int out_size, void* d_ws, size_t ws_size,
                              hipStream_t stream) {
  (void)in_sizes; (void)n_in; (void)out_size; (void)ws_size;
  const float* x  = (const float*)d_in[0];
  const float* Wq = (const float*)d_in[1];
  const float* bq = (const float*)d_in[2];
  const float* Wk = (const float*)d_in[3];
  const float* bk = (const float*)d_in[4];  (void)bk;  // softmax-invariant
  const float* Wv = (const float*)d_in[5];
  const float* bv = (const float*)d_in[6];
  const float* Wo = (const float*)d_in[7];
  const float* bo = (const float*)d_in[8];
  float* out = (float*)d_out;

  float* r   = (float*)d_ws;       // 256*4096  = 4 MiB
  float* L   = r + 1048576;        // 256*8*256 = 2 MiB
  float* Y   = L + 524288;         // 256*4096  = 4 MiB
  float* ctx = Y + 1048576;        // 256*512   = 0.5 MiB

  qr_kernel<<<dim3(16, 8), 256, 0, stream>>>(x, Wq, bq, Wk, r);
  logits_kernel<<<dim3(256, 4), 256, 0, stream>>>(x, r, L);
  y_kernel<<<dim3(256, 4), 128, 0, stream>>>(x, L, Y);
  ctx_kernel<<<dim3(16, 8), 256, 0, stream>>>(Y, Wv, bv, ctx);
  out_kernel<<<dim3(16, 8), 256, 0, stream>>>(ctx, Wo, bo, out);
}